// Round 6
// baseline (338.455 us; speedup 1.0000x reference)
//
#include <hip/hip_runtime.h>
#include <float.h>

#define NEG_SLOPE 0.2f

__device__ __forceinline__ float lrelu(float x) { return x >= 0.0f ? x : NEG_SLOPE * x; }

// ============ conv: LDS-tiled, per-channel double buffer, 1 px/thread ============
// History: every prior variant paid global-load latency inside the inner loop per
// thread (125/323/447/318/87+11 us). VGPR bins are power-of-2 (waves/SIMD = 2 at
// 129-256 regs) so TLP alone never hid it. This round: canonical stage->LDS->compute
// with a per-channel double buffer: bulk coalesced staging of the next channel's
// 4 input rows + 256 weights overlaps the current channel's FMAs; one barrier per
// channel. No channel split -> no partials, no epilogue kernel, no memset.
struct ConvSeg {
    const float* in; const float* wa; const float* wb; const float* ba; const float* bb;
    float* out;
    int CIN, H, W, right, OW, cw, nchunk, npix, blk0;
};
struct ConvTab { ConvSeg seg[10]; };

#define STR 1028   // LDS row stride in floats: max left span 4*256=1024, +4 pad (16B-aligned)

__global__ __launch_bounds__(256)
void conv_uber(ConvTab tab) {
    __shared__ float s_in[2 * 4 * STR];   // [buf][row][col]
    __shared__ float s_w[2 * 256];        // [buf][tap*16+co]
    __shared__ float s_wb[256];           // [k*16+co]
    __shared__ float s_ba[16], s_bb[16];

    int si = 0;
#pragma unroll
    for (int i = 1; i < 10; i++) if ((int)blockIdx.x >= tab.seg[i].blk0) si = i;
    const ConvSeg sg = tab.seg[si];
    const int CIN = sg.CIN, W = sg.W, OW = sg.OW;
    const int tid = threadIdx.x;

    const int rel = (int)blockIdx.x - sg.blk0;
    const int y = rel / sg.nchunk, chk = rel - y * sg.nchunk;
    const int ox0 = chk * sg.cw;                 // first output x of this chunk
    const int cwo = min(sg.cw, OW - ox0);        // outputs in this chunk
    const bool valid = tid < cwo;

    s_wb[tid] = sg.wb[(tid & 15) * 16 + (tid >> 4)];
    if (tid < 16) { s_ba[tid] = sg.ba[tid]; s_bb[tid] = sg.bb[tid]; }

    const size_t HW = (size_t)sg.H * W;
    const float* inb = sg.in + (size_t)(4 * y) * W;   // input row-group base, channel 0
    const int cbase = sg.right ? ox0 : 4 * ox0;       // first input col staged
    const int span = cwo + 3;                          // right-path staged cols

    // ---- prologue: stage channel 0 into buf 0 ----
    s_w[tid] = sg.wa[(tid & 15) * (CIN * 16) + (tid >> 4)];
    if (sg.right) {
        for (int cc = tid; cc < span; cc += 256) {
            int gc = cbase + cc;
#pragma unroll
            for (int rr = 0; rr < 4; rr++)
                s_in[rr * STR + cc] = (gc < W) ? inb[rr * W + gc] : 0.f;  // zero-pad past W
        }
    } else {
        for (int j = tid; j < cwo; j += 256) {
#pragma unroll
            for (int rr = 0; rr < 4; rr++)
                *(float4*)&s_in[rr * STR + 4 * j] = *(const float4*)&inb[rr * W + cbase + 4 * j];
        }
    }
    __syncthreads();

    float m[16];
#pragma unroll
    for (int co = 0; co < 16; co++) m[co] = 0.f;

    int buf = 0;
    for (int c = 0; c < CIN; c++) {
        const int nb = buf ^ 1;
        // ---- stage channel c+1 into buf^1 (loads issue, latency hides under FMAs) ----
        if (c + 1 < CIN) {
            s_w[nb * 256 + tid] = sg.wa[(tid & 15) * (CIN * 16) + (c + 1) * 16 + (tid >> 4)];
            const float* inc = inb + (size_t)(c + 1) * HW;
            if (sg.right) {
                for (int cc = tid; cc < span; cc += 256) {
                    int gc = cbase + cc;
#pragma unroll
                    for (int rr = 0; rr < 4; rr++)
                        s_in[nb * 4 * STR + rr * STR + cc] = (gc < W) ? inc[rr * W + gc] : 0.f;
                }
            } else {
                for (int j = tid; j < cwo; j += 256) {
#pragma unroll
                    for (int rr = 0; rr < 4; rr++)
                        *(float4*)&s_in[nb * 4 * STR + rr * STR + 4 * j] =
                            *(const float4*)&inc[rr * W + cbase + 4 * j];
                }
            }
        }
        // ---- compute channel c from buf ----
        if (valid) {
            const float* sb = s_in + buf * 4 * STR;
            float wv[16];
            if (sg.right) {
#pragma unroll
                for (int rr = 0; rr < 4; rr++)
#pragma unroll
                    for (int k = 0; k < 4; k++) wv[rr * 4 + k] = sb[rr * STR + tid + k];  // stride-1 lanes: conflict-free
            } else {
#pragma unroll
                for (int rr = 0; rr < 4; rr++) {
                    float4 f = *(const float4*)&sb[rr * STR + 4 * tid];   // aligned ds_read_b128
                    wv[rr * 4 + 0] = f.x; wv[rr * 4 + 1] = f.y;
                    wv[rr * 4 + 2] = f.z; wv[rr * 4 + 3] = f.w;
                }
            }
            const float* wc = s_w + buf * 256;
#pragma unroll
            for (int tap = 0; tap < 16; tap++) {
                float v = wv[tap];
                const float* w2 = wc + tap * 16;   // broadcast ds_read_b128 x4
#pragma unroll
                for (int co = 0; co < 16; co++) m[co] = fmaf(v, w2[co], m[co]);
            }
        }
        __syncthreads();   // staging of c+1 done; compute of c done; safe to swap
        buf = nb;
    }

    // ---- fused epilogue: bias + lrelu + 1x1 (LDS broadcast) + bias + lrelu ----
    if (valid) {
#pragma unroll
        for (int co = 0; co < 16; co++) m[co] = lrelu(m[co] + s_ba[co]);
        float o[16];
#pragma unroll
        for (int co = 0; co < 16; co++) o[co] = 0.f;
#pragma unroll
        for (int k = 0; k < 16; k++) {
            float mk = m[k];
            const float* wr = s_wb + k * 16;
#pragma unroll
            for (int co = 0; co < 16; co++) o[co] = fmaf(mk, wr[co], o[co]);
        }
        const int op = y * OW + ox0 + tid;
#pragma unroll
        for (int co = 0; co < 16; co++)
            sg.out[(size_t)co * sg.npix + op] = lrelu(o[co] + s_bb[co]);
    }
}

// ============ über cost-volume + argmin + hyp: 16 px x 16 d-chunks per block ============
struct CvSeg {
    const float* tl; const float* tr; const float* feat;
    const float* dw; const float* db;
    float* cv; float* hyp;
    int h, w4, w, D, gpc, CF, blk0;
};
struct CvTab { CvSeg seg[5]; };

__global__ __launch_bounds__(256)
void cv_hyp_uber(CvTab tab) {
    __shared__ float smin[256];
    __shared__ int sarg[256];

    int si = 0;
#pragma unroll
    for (int i = 1; i < 5; i++) if ((int)blockIdx.x >= tab.seg[i].blk0) si = i;
    const CvSeg sg = tab.seg[si];

    const int npix = sg.h * sg.w4;
    const int p = threadIdx.x & 15, chunk = threadIdx.x >> 4;
    const int pix = ((int)blockIdx.x - sg.blk0) * 16 + p;
    const bool valid = pix < npix;

    float mloc = FLT_MAX; int aloc = 0;
    if (valid) {
        int y = pix / sg.w4, j = pix - y * sg.w4;
        float tlv[16]; float sumabs = 0.f;
#pragma unroll
        for (int c = 0; c < 16; c++) { tlv[c] = sg.tl[(size_t)c * npix + pix]; sumabs += fabsf(tlv[c]); }

        int ngroups = sg.D >> 2;
        int g0 = chunk * sg.gpc;
        int g1 = min(ngroups, g0 + sg.gpc);
        const float* trrow = sg.tr + (size_t)y * sg.w;
        int hw = sg.h * sg.w;

        float carry[16];
        int b0 = 4 * j - 4 * g0;
        if (g0 < g1 && b0 >= 0) {
#pragma unroll
            for (int c = 0; c < 16; c++) carry[c] = trrow[(size_t)c * hw + b0];
        }
        for (int g = g0; g < g1; g++) {
            int b = 4 * j - 4 * g;
            float a0, a1, a2, a3;
            if (b >= 4) {
                a0 = a1 = a2 = a3 = 0.f;
#pragma unroll
                for (int c = 0; c < 16; c++) {
                    float4 f0 = *(const float4*)(trrow + (size_t)c * hw + (b - 4));
                    float tv = tlv[c];
                    a0 += fabsf(tv - carry[c]);
                    a1 += fabsf(tv - f0.w);
                    a2 += fabsf(tv - f0.z);
                    a3 += fabsf(tv - f0.y);
                    carry[c] = f0.x;
                }
            } else if (b == 0) {
                a0 = 0.f; a1 = a2 = a3 = sumabs;
#pragma unroll
                for (int c = 0; c < 16; c++) a0 += fabsf(tlv[c] - carry[c]);
            } else {
                a0 = a1 = a2 = a3 = sumabs;
            }
            float* cvp = sg.cv + (size_t)(4 * g) * npix + pix;
            cvp[0] = a0; cvp[npix] = a1; cvp[2 * (size_t)npix] = a2; cvp[3 * (size_t)npix] = a3;
            if (a0 < mloc) { mloc = a0; aloc = 4 * g; }
            if (a1 < mloc) { mloc = a1; aloc = 4 * g + 1; }
            if (a2 < mloc) { mloc = a2; aloc = 4 * g + 2; }
            if (a3 < mloc) { mloc = a3; aloc = 4 * g + 3; }
        }
    }
    smin[threadIdx.x] = mloc;
    sarg[threadIdx.x] = aloc;
    __syncthreads();

    if (threadIdx.x < 16 && valid) {
        float mn = smin[threadIdx.x]; int arg = sarg[threadIdx.x];
#pragma unroll
        for (int c2 = 1; c2 < 16; c2++) {    // ascending chunk = ascending d; strict <
            float v = smin[c2 * 16 + threadIdx.x];
            if (v < mn) { mn = v; arg = sarg[c2 * 16 + threadIdx.x]; }
        }
        float acc[13];
#pragma unroll
        for (int o = 0; o < 13; o++) acc[o] = sg.dw[o * (sg.CF + 1)] * mn;
        for (int c = 0; c < sg.CF; c++) {
            float v = sg.feat[(size_t)c * npix + pix];
#pragma unroll
            for (int o = 0; o < 13; o++) acc[o] = fmaf(v, sg.dw[o * (sg.CF + 1) + 1 + c], acc[o]);
        }
        sg.hyp[pix] = (float)arg;
        sg.hyp[npix + pix] = 0.f;
        sg.hyp[2 * (size_t)npix + pix] = 0.f;
#pragma unroll
        for (int o = 0; o < 13; o++) sg.hyp[(size_t)(3 + o) * npix + pix] = lrelu(acc[o] + sg.db[o]);
    }
}

extern "C" void kernel_launch(void* const* d_in, const int* in_sizes, int n_in,
                              void* d_out, int out_size, void* d_ws, size_t ws_size,
                              hipStream_t stream) {
    (void)in_sizes; (void)n_in; (void)out_size; (void)ws_size;
    float* out = (float*)d_out;
    float* ws = (float*)d_ws;

    const int C[5] = {32, 24, 24, 16, 16};
    const int H[5] = {24, 48, 96, 192, 384};
    const int W[5] = {80, 160, 320, 640, 1280};
    const int D[5] = {20, 40, 80, 160, 320};
    const int wa_i[5] = {10, 14, 18, 22, 26};
    const int dw_i[5] = {30, 32, 34, 36, 38};

    const size_t cv_off[5]  = {0, 2400, 21600, 175200, 1404000};
    const size_t hyp_off[5] = {11234400, 11236320, 11244000, 11274720, 11397600};
    const size_t tl_off[5] = {0, 9600, 48000, 201600, 816000};
    const size_t tr_off[5] = {1920, 17280, 78720, 324480, 1307520};

    const float* fl[5] = {(const float*)d_in[0], (const float*)d_in[1], (const float*)d_in[2],
                          (const float*)d_in[3], (const float*)d_in[4]};
    const float* fr[5] = {(const float*)d_in[5], (const float*)d_in[6], (const float*)d_in[7],
                          (const float*)d_in[8], (const float*)d_in[9]};

    // ---- conv table: biggest segments first; one output-row chunk per block ----
    const int ord_lvl[10]  = {4, 4, 3, 3, 2, 2, 1, 1, 0, 0};
    const int ord_side[10] = {1, 0, 1, 0, 1, 0, 1, 0, 1, 0};   // 1 = right
    ConvTab ct;
    int blk = 0;
    for (int i = 0; i < 10; i++) {
        int l = ord_lvl[i]; bool right = ord_side[i];
        ConvSeg& s = ct.seg[i];
        s.in = right ? fr[l] : fl[l];
        s.wa = (const float*)d_in[wa_i[l]];
        s.ba = (const float*)d_in[wa_i[l] + 1];
        s.wb = (const float*)d_in[wa_i[l] + 2];
        s.bb = (const float*)d_in[wa_i[l] + 3];
        s.out = ws + (right ? tr_off[l] : tl_off[l]);
        s.CIN = C[l]; s.H = H[l]; s.W = W[l];
        s.right = right ? 1 : 0;
        int OH = H[l] / 4;
        s.OW = right ? W[l] : W[l] / 4;
        s.nchunk = (s.OW + 255) / 256;
        s.cw = (s.OW + s.nchunk - 1) / s.nchunk;   // near-even chunks (e.g. 320 -> 2x160)
        s.npix = OH * s.OW;
        s.blk0 = blk;
        blk += OH * s.nchunk;
    }
    conv_uber<<<blk, 256, 0, stream>>>(ct);

    // ---- cv table: level 1 (biggest) first; 16 px x 16 d-chunks per block ----
    const float* feat[5] = {ws + tl_off[0], ws + tl_off[1], fl[0], fl[1], fl[2]};
    const int   CF[5]    = {16, 16, 32, 24, 24};
    CvTab vt;
    blk = 0;
    for (int i = 0; i < 5; i++) {
        int l = 4 - i;
        CvSeg& s = vt.seg[i];
        s.tl = ws + tl_off[l]; s.tr = ws + tr_off[l];
        s.feat = feat[l];
        s.dw = (const float*)d_in[dw_i[l]];
        s.db = (const float*)d_in[dw_i[l] + 1];
        s.cv = out + cv_off[l]; s.hyp = out + hyp_off[l];
        s.h = H[l] / 4; s.w4 = W[l] / 4; s.w = W[l]; s.D = D[l];
        int ngroups = D[l] / 4;
        s.gpc = (ngroups + 15) / 16;
        s.CF = CF[l];
        s.blk0 = blk;
        blk += (s.h * s.w4 + 15) / 16;
    }
    cv_hyp_uber<<<blk, 256, 0, stream>>>(vt);
}

// Round 7
// 315.931 us; speedup vs baseline: 1.0713x; 1.0713x over previous
//
#include <hip/hip_runtime.h>
#include <float.h>

#define NEG_SLOPE 0.2f

__device__ __forceinline__ float lrelu(float x) { return x >= 0.0f ? x : NEG_SLOPE * x; }

// ============ conv: LDS-tiled, co-quad per wave, 4 px/thread, T14 reg-staging ============
// r6 post-mortem: P=1 meant 64 broadcast weight b128 per wave per channel -> LDS pipe
// (1/CU, shared by 4 waves) 7x oversubscribed vs VALU; VALUBusy 15%. Fix: block =
// 256 px x 16 co, wave w owns co quad 4w..4w+3, thread holds m[4px][4co] -> 16 weight
// b128 + 8 input b128 per wave per channel vs 512 VALU cyc. Staging is T14-split
// (global->reg issued BEFORE compute, reg->LDS written after) so the per-channel
// barrier drain hides under FMAs. 1x1 needs all 16 mid channels -> waves exchange
// m via LDS (reusing input buffer) before the fused epilogue.
struct ConvSeg {
    const float* in; const float* wa; const float* wb; const float* ba; const float* bb;
    float* out;
    int CIN, H, W, right, OW, cw, nchunk, npix, blk0;
};
struct ConvTab { ConvSeg seg[10]; };

#define SROW 1040   // LDS row floats: left needs 4*256=1024, right 259; pad to 1040

__global__ __launch_bounds__(256)
void conv_uber(ConvTab tab) {
    __shared__ float s_in[2][4][SROW];   // input rows, double-buffered
    __shared__ float s_w[2][256];        // [tap*16+co], double-buffered
    __shared__ float s_wb[256];          // 1x1 weights [k*16+co]
    __shared__ float s_ba[16], s_bb[16];

    int si = 0;
#pragma unroll
    for (int i = 1; i < 10; i++) if ((int)blockIdx.x >= tab.seg[i].blk0) si = i;
    const ConvSeg sg = tab.seg[si];
    const int CIN = sg.CIN, W = sg.W, OW = sg.OW;
    const int tid = threadIdx.x, lane = tid & 63;
    const int cb = (tid >> 6) * 4;                    // this wave's co quad

    const int rel = (int)blockIdx.x - sg.blk0;
    const int y = rel / sg.nchunk, chk = rel - y * sg.nchunk;
    const int ox0 = chk * sg.cw;
    const int cwo = min(sg.cw, OW - ox0);             // outputs in this chunk (<=256)

    s_wb[tid] = sg.wb[(tid & 15) * 16 + (tid >> 4)];
    if (tid < 16) { s_ba[tid] = sg.ba[tid]; s_bb[tid] = sg.bb[tid]; }

    const size_t HW = (size_t)sg.H * W;
    const float* inb = sg.in + (size_t)(4 * y) * W;
    const int cbase = sg.right ? ox0 : 4 * ox0;
    const int span = cwo + 3;                         // right-path staged cols

    // ---- prologue: stage channel 0 directly ----
    s_w[0][tid] = sg.wa[(tid & 15) * (CIN * 16) + (tid >> 4)];
    if (sg.right) {
        for (int cc = tid; cc < span; cc += 256) {
            int gc = cbase + cc;
#pragma unroll
            for (int r = 0; r < 4; r++)
                s_in[0][r][cc] = (gc < W) ? inb[r * W + gc] : 0.f;
        }
    } else if (tid < cwo) {
#pragma unroll
        for (int r = 0; r < 4; r++)
            *(float4*)&s_in[0][r][4 * tid] = *(const float4*)&inb[r * W + cbase + 4 * tid];
    }
    __syncthreads();

    float m[4][4];   // [px slot][co in quad]
#pragma unroll
    for (int i = 0; i < 4; i++)
#pragma unroll
        for (int q = 0; q < 4; q++) m[i][q] = 0.f;

    int buf = 0;
    for (int c = 0; c < CIN; c++) {
        const int nb = buf ^ 1;
        // ---- T14 stage-issue: next channel global -> regs (no LDS write yet) ----
        float rw = 0.f, rs[16];
        const bool more = (c + 1 < CIN);
        if (more) {
            rw = sg.wa[(tid & 15) * (CIN * 16) + (c + 1) * 16 + (tid >> 4)];
            const float* inc = inb + (size_t)(c + 1) * HW;
            if (sg.right) {
                int gc = cbase + tid;
#pragma unroll
                for (int r = 0; r < 4; r++)
                    rs[r] = (tid < span && gc < W) ? inc[r * W + gc] : 0.f;
                int gc2 = cbase + tid + 256;
#pragma unroll
                for (int r = 0; r < 4; r++)
                    rs[4 + r] = (tid + 256 < span && gc2 < W) ? inc[r * W + gc2] : 0.f;
            } else if (tid < cwo) {
#pragma unroll
                for (int r = 0; r < 4; r++) {
                    float4 f = *(const float4*)&inc[r * W + cbase + 4 * tid];
                    rs[4 * r] = f.x; rs[4 * r + 1] = f.y; rs[4 * r + 2] = f.z; rs[4 * r + 3] = f.w;
                }
            }
        }
        // ---- compute channel c (LDS only; independent of in-flight loads) ----
        if (sg.right) {
            // px = ox0 + 4*lane + i; cols 4l..4l+6; conflict-free b128 (16B lane stride)
#pragma unroll
            for (int r = 0; r < 4; r++) {
                float4 a = *(const float4*)&s_in[buf][r][4 * lane];
                float4 b = *(const float4*)&s_in[buf][r][4 * lane + 4];
                float v[8] = {a.x, a.y, a.z, a.w, b.x, b.y, b.z, b.w};
#pragma unroll
                for (int kx = 0; kx < 4; kx++) {
                    float4 wq = *(const float4*)&s_w[buf][(r * 4 + kx) * 16 + cb];  // broadcast
#pragma unroll
                    for (int i = 0; i < 4; i++) {
                        float vv = v[i + kx];
                        m[i][0] = fmaf(vv, wq.x, m[i][0]);
                        m[i][1] = fmaf(vv, wq.y, m[i][1]);
                        m[i][2] = fmaf(vv, wq.z, m[i][2]);
                        m[i][3] = fmaf(vv, wq.w, m[i][3]);
                    }
                }
            }
        } else {
            // px = ox0 + lane + 64*i (strided): b128 at 16B lane stride, conflict-free
#pragma unroll
            for (int i = 0; i < 4; i++) {
                if (64 * i >= cwo) break;   // wave-uniform bound
                const int col = 4 * (lane + 64 * i);
                float4 q0 = *(const float4*)&s_in[buf][0][col];
                float4 q1 = *(const float4*)&s_in[buf][1][col];
                float4 q2 = *(const float4*)&s_in[buf][2][col];
                float4 q3 = *(const float4*)&s_in[buf][3][col];
                float qa[16] = {q0.x, q0.y, q0.z, q0.w, q1.x, q1.y, q1.z, q1.w,
                                q2.x, q2.y, q2.z, q2.w, q3.x, q3.y, q3.z, q3.w};
#pragma unroll
                for (int tap = 0; tap < 16; tap++) {
                    float4 wq = *(const float4*)&s_w[buf][tap * 16 + cb];
                    float vv = qa[tap];
                    m[i][0] = fmaf(vv, wq.x, m[i][0]);
                    m[i][1] = fmaf(vv, wq.y, m[i][1]);
                    m[i][2] = fmaf(vv, wq.z, m[i][2]);
                    m[i][3] = fmaf(vv, wq.w, m[i][3]);
                }
            }
        }
        // ---- T14 stage-write: regs -> LDS next buffer (vmcnt wait lands HERE) ----
        if (more) {
            s_w[nb][tid] = rw;
            if (sg.right) {
                if (tid < span)
#pragma unroll
                    for (int r = 0; r < 4; r++) s_in[nb][r][tid] = rs[r];
                if (tid + 256 < span)
#pragma unroll
                    for (int r = 0; r < 4; r++) s_in[nb][r][tid + 256] = rs[4 + r];
            } else if (tid < cwo) {
#pragma unroll
                for (int r = 0; r < 4; r++)
                    *(float4*)&s_in[nb][r][4 * tid] =
                        make_float4(rs[4 * r], rs[4 * r + 1], rs[4 * r + 2], rs[4 * r + 3]);
            }
        }
        __syncthreads();
        buf = nb;
    }

    // ---- cross-wave exchange: full 16-channel vector per px via LDS ----
    float* x_lds = &s_in[0][0][0];   // 4096 floats needed, 4160 available
    if (sg.right) {
#pragma unroll
        for (int q = 0; q < 4; q++)
            *(float4*)&x_lds[(cb + q) * 256 + 4 * lane] =
                make_float4(m[0][q], m[1][q], m[2][q], m[3][q]);
    } else {
#pragma unroll
        for (int i = 0; i < 4; i++) {
            if (64 * i >= cwo) break;
#pragma unroll
            for (int q = 0; q < 4; q++)
                x_lds[(cb + q) * 256 + lane + 64 * i] = m[i][q];
        }
    }
    __syncthreads();

    // ---- fused epilogue: 1 px/thread: bias+lrelu, 1x1 (broadcast), bias+lrelu ----
    float x[16];
#pragma unroll
    for (int k = 0; k < 16; k++) x[k] = lrelu(x_lds[k * 256 + tid] + s_ba[k]);
    float o[16];
#pragma unroll
    for (int co = 0; co < 16; co++) o[co] = 0.f;
#pragma unroll
    for (int k = 0; k < 16; k++) {
        float mk = x[k];
        const float* wr = s_wb + k * 16;
#pragma unroll
        for (int co = 0; co < 16; co++) o[co] = fmaf(mk, wr[co], o[co]);
    }
    if (tid < cwo) {
        const int op = y * OW + ox0 + tid;
#pragma unroll
        for (int co = 0; co < 16; co++)
            sg.out[(size_t)co * sg.npix + op] = lrelu(o[co] + s_bb[co]);
    }
}

// ============ über cost-volume + argmin + hyp: 16 px x 16 d-chunks per block ============
struct CvSeg {
    const float* tl; const float* tr; const float* feat;
    const float* dw; const float* db;
    float* cv; float* hyp;
    int h, w4, w, D, gpc, CF, blk0;
};
struct CvTab { CvSeg seg[5]; };

__global__ __launch_bounds__(256)
void cv_hyp_uber(CvTab tab) {
    __shared__ float smin[256];
    __shared__ int sarg[256];

    int si = 0;
#pragma unroll
    for (int i = 1; i < 5; i++) if ((int)blockIdx.x >= tab.seg[i].blk0) si = i;
    const CvSeg sg = tab.seg[si];

    const int npix = sg.h * sg.w4;
    const int p = threadIdx.x & 15, chunk = threadIdx.x >> 4;
    const int pix = ((int)blockIdx.x - sg.blk0) * 16 + p;
    const bool valid = pix < npix;

    float mloc = FLT_MAX; int aloc = 0;
    if (valid) {
        int y = pix / sg.w4, j = pix - y * sg.w4;
        float tlv[16]; float sumabs = 0.f;
#pragma unroll
        for (int c = 0; c < 16; c++) { tlv[c] = sg.tl[(size_t)c * npix + pix]; sumabs += fabsf(tlv[c]); }

        int ngroups = sg.D >> 2;
        int g0 = chunk * sg.gpc;
        int g1 = min(ngroups, g0 + sg.gpc);
        const float* trrow = sg.tr + (size_t)y * sg.w;
        int hw = sg.h * sg.w;

        float carry[16];
        int b0 = 4 * j - 4 * g0;
        if (g0 < g1 && b0 >= 0) {
#pragma unroll
            for (int c = 0; c < 16; c++) carry[c] = trrow[(size_t)c * hw + b0];
        }
        for (int g = g0; g < g1; g++) {
            int b = 4 * j - 4 * g;
            float a0, a1, a2, a3;
            if (b >= 4) {
                a0 = a1 = a2 = a3 = 0.f;
#pragma unroll
                for (int c = 0; c < 16; c++) {
                    float4 f0 = *(const float4*)(trrow + (size_t)c * hw + (b - 4));
                    float tv = tlv[c];
                    a0 += fabsf(tv - carry[c]);
                    a1 += fabsf(tv - f0.w);
                    a2 += fabsf(tv - f0.z);
                    a3 += fabsf(tv - f0.y);
                    carry[c] = f0.x;
                }
            } else if (b == 0) {
                a0 = 0.f; a1 = a2 = a3 = sumabs;
#pragma unroll
                for (int c = 0; c < 16; c++) a0 += fabsf(tlv[c] - carry[c]);
            } else {
                a0 = a1 = a2 = a3 = sumabs;
            }
            float* cvp = sg.cv + (size_t)(4 * g) * npix + pix;
            cvp[0] = a0; cvp[npix] = a1; cvp[2 * (size_t)npix] = a2; cvp[3 * (size_t)npix] = a3;
            if (a0 < mloc) { mloc = a0; aloc = 4 * g; }
            if (a1 < mloc) { mloc = a1; aloc = 4 * g + 1; }
            if (a2 < mloc) { mloc = a2; aloc = 4 * g + 2; }
            if (a3 < mloc) { mloc = a3; aloc = 4 * g + 3; }
        }
    }
    smin[threadIdx.x] = mloc;
    sarg[threadIdx.x] = aloc;
    __syncthreads();

    if (threadIdx.x < 16 && valid) {
        float mn = smin[threadIdx.x]; int arg = sarg[threadIdx.x];
#pragma unroll
        for (int c2 = 1; c2 < 16; c2++) {    // ascending chunk = ascending d; strict <
            float v = smin[c2 * 16 + threadIdx.x];
            if (v < mn) { mn = v; arg = sarg[c2 * 16 + threadIdx.x]; }
        }
        float acc[13];
#pragma unroll
        for (int o = 0; o < 13; o++) acc[o] = sg.dw[o * (sg.CF + 1)] * mn;
        for (int c = 0; c < sg.CF; c++) {
            float v = sg.feat[(size_t)c * npix + pix];
#pragma unroll
            for (int o = 0; o < 13; o++) acc[o] = fmaf(v, sg.dw[o * (sg.CF + 1) + 1 + c], acc[o]);
        }
        sg.hyp[pix] = (float)arg;
        sg.hyp[npix + pix] = 0.f;
        sg.hyp[2 * (size_t)npix + pix] = 0.f;
#pragma unroll
        for (int o = 0; o < 13; o++) sg.hyp[(size_t)(3 + o) * npix + pix] = lrelu(acc[o] + sg.db[o]);
    }
}

extern "C" void kernel_launch(void* const* d_in, const int* in_sizes, int n_in,
                              void* d_out, int out_size, void* d_ws, size_t ws_size,
                              hipStream_t stream) {
    (void)in_sizes; (void)n_in; (void)out_size; (void)ws_size;
    float* out = (float*)d_out;
    float* ws = (float*)d_ws;

    const int C[5] = {32, 24, 24, 16, 16};
    const int H[5] = {24, 48, 96, 192, 384};
    const int W[5] = {80, 160, 320, 640, 1280};
    const int D[5] = {20, 40, 80, 160, 320};
    const int wa_i[5] = {10, 14, 18, 22, 26};
    const int dw_i[5] = {30, 32, 34, 36, 38};

    const size_t cv_off[5]  = {0, 2400, 21600, 175200, 1404000};
    const size_t hyp_off[5] = {11234400, 11236320, 11244000, 11274720, 11397600};
    const size_t tl_off[5] = {0, 9600, 48000, 201600, 816000};
    const size_t tr_off[5] = {1920, 17280, 78720, 324480, 1307520};

    const float* fl[5] = {(const float*)d_in[0], (const float*)d_in[1], (const float*)d_in[2],
                          (const float*)d_in[3], (const float*)d_in[4]};
    const float* fr[5] = {(const float*)d_in[5], (const float*)d_in[6], (const float*)d_in[7],
                          (const float*)d_in[8], (const float*)d_in[9]};

    // ---- conv table: biggest segments first; 256 output px per block ----
    const int ord_lvl[10]  = {4, 4, 3, 3, 2, 2, 1, 1, 0, 0};
    const int ord_side[10] = {1, 0, 1, 0, 1, 0, 1, 0, 1, 0};   // 1 = right
    ConvTab ct;
    int blk = 0;
    for (int i = 0; i < 10; i++) {
        int l = ord_lvl[i]; bool right = ord_side[i];
        ConvSeg& s = ct.seg[i];
        s.in = right ? fr[l] : fl[l];
        s.wa = (const float*)d_in[wa_i[l]];
        s.ba = (const float*)d_in[wa_i[l] + 1];
        s.wb = (const float*)d_in[wa_i[l] + 2];
        s.bb = (const float*)d_in[wa_i[l] + 3];
        s.out = ws + (right ? tr_off[l] : tl_off[l]);
        s.CIN = C[l]; s.H = H[l]; s.W = W[l];
        s.right = right ? 1 : 0;
        int OH = H[l] / 4;
        s.OW = right ? W[l] : W[l] / 4;
        s.nchunk = (s.OW + 255) / 256;
        int cwr = (s.OW + s.nchunk - 1) / s.nchunk;
        s.cw = (cwr + 3) & ~3;                     // multiple of 4 for px grouping
        s.npix = OH * s.OW;
        s.blk0 = blk;
        blk += OH * s.nchunk;
    }
    conv_uber<<<blk, 256, 0, stream>>>(ct);

    // ---- cv table: level 1 (biggest) first; 16 px x 16 d-chunks per block ----
    const float* feat[5] = {ws + tl_off[0], ws + tl_off[1], fl[0], fl[1], fl[2]};
    const int   CF[5]    = {16, 16, 32, 24, 24};
    CvTab vt;
    blk = 0;
    for (int i = 0; i < 5; i++) {
        int l = 4 - i;
        CvSeg& s = vt.seg[i];
        s.tl = ws + tl_off[l]; s.tr = ws + tr_off[l];
        s.feat = feat[l];
        s.dw = (const float*)d_in[dw_i[l]];
        s.db = (const float*)d_in[dw_i[l] + 1];
        s.cv = out + cv_off[l]; s.hyp = out + hyp_off[l];
        s.h = H[l] / 4; s.w4 = W[l] / 4; s.w = W[l]; s.D = D[l];
        int ngroups = D[l] / 4;
        s.gpc = (ngroups + 15) / 16;
        s.CF = CF[l];
        s.blk0 = blk;
        blk += (s.h * s.w4 + 15) / 16;
    }
    cv_hyp_uber<<<blk, 256, 0, stream>>>(vt);
}